// Round 9
// baseline (35.326 us; speedup 1.0000x reference)
//
#include <hip/hip_runtime.h>

typedef unsigned short ushort_t;
typedef unsigned int uint_t;
typedef __bf16 bf16x8 __attribute__((ext_vector_type(8)));
typedef float f32x4 __attribute__((ext_vector_type(4)));

#define H 256
#define RPB 32      // batch rows per block (2 row-tiles of 16)
#define NBLK 128    // 4096 / RPB

// output layout (f32): [nb 4096][bdot 4096][y 4096*256][yy 4096*64]
#define NB_OFF 0
#define BDOT_OFF 4096
#define Y_OFF 8192
#define YY_OFF (8192 + 4096 * 256)

__device__ __forceinline__ ushort_t f2bf(float x) {
    union { float f; uint_t u; } c; c.f = x;
    uint_t r = (c.u + 0x7FFFu + ((c.u >> 16) & 1u)) >> 16;  // RNE
    return (ushort_t)r;
}
__device__ __forceinline__ float bf2f(ushort_t v) {
    union { uint_t u; float f; } c; c.u = ((uint_t)v) << 16;
    return c.f;
}

// ws layout (ushort/bf16 units)
#define O_W1b  0        // [256][64]   orig (B for z)
#define O_W1T  16384    // [64][256]   W1T[i][g] = w1[g][i]
#define O_W2ab 32768    // [256][256]  orig
#define O_W2bb 98304
#define O_W3ab 163840
#define O_W2aT 229376   // [g][h] = w2a[h][g]
#define O_W2bT 294912
#define O_W3aT 360448   // [g][o] = wout[o]*w3a[o][g]   (wout folded)
#define O_W3sb 425984   // [256][64] orig
#define O_W3sT 442368   // [i][o] = wout[o]*w3s[o][i]   (wout folded)

__global__ __launch_bounds__(256) void prep_weights(
    const float* __restrict__ w1, const float* __restrict__ w2a,
    const float* __restrict__ w2b, const float* __restrict__ w3a,
    const float* __restrict__ w3s, const float* __restrict__ wout,
    ushort_t* __restrict__ ws) {
    __shared__ float tile[32][65];
    int b = blockIdx.x;
    const float* src; int Oo, Ot, C, t; bool scl;
    if (b < 32)       { src = w2a; Oo = O_W2ab; Ot = O_W2aT; C = 256; t = b;       scl = false; }
    else if (b < 64)  { src = w2b; Oo = O_W2bb; Ot = O_W2bT; C = 256; t = b - 32;  scl = false; }
    else if (b < 96)  { src = w3a; Oo = O_W3ab; Ot = O_W3aT; C = 256; t = b - 64;  scl = true;  }
    else if (b < 104) { src = w1;  Oo = O_W1b;  Ot = O_W1T;  C = 64;  t = b - 96;  scl = false; }
    else              { src = w3s; Oo = O_W3sb; Ot = O_W3sT; C = 64;  t = b - 104; scl = true;  }
    int tr, tc;
    if (C == 256) { tr = t >> 2; tc = t & 3; } else { tr = t; tc = 0; }
    int r0 = tr * 32, c0 = tc * 64;
    const int tid = threadIdx.x;

    union pack8 { ushort_t u[8]; uint4 q; };
    {
        int r = tid >> 3, c8 = (tid & 7) << 3;
        const float* s = src + (r0 + r) * C + c0 + c8;
        pack8 p;
#pragma unroll
        for (int j = 0; j < 8; j++) { float v = s[j]; tile[r][c8 + j] = v; p.u[j] = f2bf(v); }
        *(uint4*)(ws + Oo + (r0 + r) * C + c0 + c8) = p.q;
    }
    __syncthreads();
    {
        int cc = tid >> 2, r8 = (tid & 3) << 3;
        pack8 p;
#pragma unroll
        for (int j = 0; j < 8; j++) {
            float v = tile[r8 + j][cc];
            if (scl) v *= wout[r0 + r8 + j];
            p.u[j] = f2bf(v);
        }
        *(uint4*)(ws + Ot + (c0 + cc) * 256 + r0 + r8) = p.q;
    }
}

// dynamic smem layout (ushort units)
#define RS 4            // ring slots per wave (512 ushorts = 1KB each)
#define RA 4            // units in flight per wave
#define U_RING 0        // 16 waves * 4 * 512 = 32768
#define U_Y    32768    // y1 -> z1_3 (alias)           [32*256]
#define U_Z12  40960    // z1_2 -> t*z1_2; then FJ1 f32 (alias)
#define U_Z22  49152    // z2_2 -> t*z2_2; then FJ2 f32 (alias)
#define U_Z23  57344    // z2_3 (v)
#define U_U    65536    // y2 -> c2 (alias)
#define U_XD   73728    // f32 [2048]
#define U_NB   77824    // f32 [32]
#define SMEM_USHORTS 77888
#define SMEM_BYTES (SMEM_USHORTS * 2)

__device__ __forceinline__ void gload16(const ushort_t* g, ushort_t* l) {
    __builtin_amdgcn_global_load_lds(
        (const __attribute__((address_space(1))) void*)g,
        (__attribute__((address_space(3))) void*)l, 16, 0, 0);
}

template <int N> __device__ __forceinline__ void vwait() {
    if constexpr (N == 3) asm volatile("s_waitcnt vmcnt(3)" ::: "memory");
    else if constexpr (N == 2) asm volatile("s_waitcnt vmcnt(2)" ::: "memory");
    else if constexpr (N == 1) asm volatile("s_waitcnt vmcnt(1)" ::: "memory");
    else asm volatile("s_waitcnt vmcnt(0)" ::: "memory");
}

#define PHASE_BARRIER() do { \
    asm volatile("s_waitcnt lgkmcnt(0)" ::: "memory"); \
    __builtin_amdgcn_sched_barrier(0); \
    __builtin_amdgcn_s_barrier(); \
    __builtin_amdgcn_sched_barrier(0); \
} while (0)

__device__ __forceinline__ int posw(int r, int c) { return r * H + (c ^ ((r & 7) << 3)); }

// Continuous-ring staged GEMM phase: 16 units (2 matrices x 8 k-chunks of 32).
// Global unit order u = P*16 + k; slot = u & 3 (RS=4). Restage of unit u+4
// targets the slot read THIS iteration, guarded by lgkmcnt(2) (the b-read is
// the oldest of this iter's 3 ds_reads; in-order completion => b done).
// Two row-tiles (rows 0-15 / 16-31) share every staged B fragment.
template <int P, bool SUM>
__device__ __forceinline__ void ring_phase(
    const ushort_t* __restrict__ gm0, const ushort_t* __restrict__ gm1,
    const ushort_t* __restrict__ gn0, const ushort_t* __restrict__ gn1,
    const ushort_t* aM0, const ushort_t* aM1,
    ushort_t* rw, int srcoff, int boff, int kq, int sw,
    f32x4& a00, f32x4& a01, f32x4& a10, f32x4& a11) {
    const int arow0 = (/*row16*/ boff >> 5) * H;   // row16 = boff/32 (boff = row16*32 + xor-octet)
    const int arow1 = arow0 + 16 * H;
#pragma unroll
    for (int k = 0; k < 16; ++k) {
        const int u = P * 16 + k;
        if (P == 2) {
            if (k < 13) vwait<3>();
            else if (k == 13) vwait<2>();
            else if (k == 14) vwait<1>();
            else vwait<0>();
        } else {
            vwait<3>();
        }
        __builtin_amdgcn_sched_barrier(0);
        bf16x8 b = *(const bf16x8*)(rw + (u & 3) * 512 + boff);
        const ushort_t* am = (k & 1) ? aM1 : aM0;
        const int ko = (((k >> 1) << 5) + kq) ^ sw;
        bf16x8 a0 = *(const bf16x8*)(am + arow0 + ko);
        bf16x8 a1 = *(const bf16x8*)(am + arow1 + ko);
        if (u + RA < 48) {
            asm volatile("s_waitcnt lgkmcnt(2)" ::: "memory");
            __builtin_amdgcn_sched_barrier(0);
            const int k4 = k + RA;
            const ushort_t* g = (k4 < 16) ? ((k4 & 1) ? gm1 : gm0)
                                          : ((k4 & 1) ? gn1 : gn0);
            const int cc = (k4 & 15) >> 1;
            gload16(g + srcoff + (cc << 5), rw + ((u + RA) & 3) * 512);
        }
        if ((k & 1) == 0 || SUM) {
            a00 = __builtin_amdgcn_mfma_f32_16x16x32_bf16(a0, b, a00, 0, 0, 0);
            a01 = __builtin_amdgcn_mfma_f32_16x16x32_bf16(a1, b, a01, 0, 0, 0);
        } else {
            a10 = __builtin_amdgcn_mfma_f32_16x16x32_bf16(a0, b, a10, 0, 0, 0);
            a11 = __builtin_amdgcn_mfma_f32_16x16x32_bf16(a1, b, a11, 0, 0, 0);
        }
    }
}

// register-path tile GEMM (small matrices), batched loads + sched fence
template <int NF, int STRA, int STRB>
__device__ __forceinline__ void gemm_one(const ushort_t* sA, const ushort_t* __restrict__ B0,
                                         int lane, int k0, f32x4& acc0) {
    const int row = lane & 15;
    const int kq = (lane >> 4) << 3;
    const int sw = (row & 7) << 3;
    bf16x8 b0[NF], a[NF];
    const ushort_t* bp0 = B0 + row * STRB + k0 + kq;
    const ushort_t* ap = sA + row * STRA;
#pragma unroll
    for (int i = 0; i < NF; i++) b0[i] = *(const bf16x8*)(bp0 + i * 32);
#pragma unroll
    for (int i = 0; i < NF; i++) a[i] = *(const bf16x8*)(ap + ((k0 + i * 32 + kq) ^ sw));
    __builtin_amdgcn_sched_barrier(0);
#pragma unroll
    for (int i = 0; i < NF; i++)
        acc0 = __builtin_amdgcn_mfma_f32_16x16x32_bf16(a[i], b0[i], acc0, 0, 0, 0);
}

__global__ __launch_bounds__(1024) void net_main(
    const float* __restrict__ x, const float* __restrict__ xd,
    const float* __restrict__ b1, const float* __restrict__ b2a,
    const float* __restrict__ b2b, const float* __restrict__ b3a,
    const float* __restrict__ b3s, const float* __restrict__ wout,
    const float* __restrict__ scalar, const ushort_t* __restrict__ ws,
    float* __restrict__ out) {
    extern __shared__ __align__(16) ushort_t smem[];
    ushort_t* sY   = smem + U_Y;    // y1, then z1_3
    ushort_t* sZ12 = smem + U_Z12;  // z1_2 -> t*z1_2, then FJ1
    ushort_t* sZ22 = smem + U_Z22;  // z2_2 -> t*z2_2, then FJ2
    ushort_t* sZ23 = smem + U_Z23;  // z2_3 (v)
    ushort_t* sU   = smem + U_U;    // y2, then c2
    float* sXd = (float*)(smem + U_XD);
    float* sNB = (float*)(smem + U_NB);

    const int tid = threadIdx.x;
    const int wid = tid >> 6;     // 0..15
    const int lane = tid & 63;
    const int row16 = lane & 15;  // MFMA D column-within-tile
    const int rq = lane >> 4;     // MFMA D row = rq*4 + i
    const int R0 = blockIdx.x * RPB;
    const int n0 = wid * 16;      // this wave's 16-col tile
    const int kq = rq << 3;
    const int sw = (row16 & 7) << 3;

    ushort_t* rw = smem + U_RING + wid * (RS * 512);
    const int nsrc = (wid << 4) + (lane >> 2);
    const int srcoff = nsrc * 256 + (((lane & 3) ^ (nsrc & 3)) << 3);
    const int boff = row16 * 32 + (kq ^ ((row16 & 3) << 3));

    const ushort_t* gW2ab = ws + O_W2ab;
    const ushort_t* gW2bb = ws + O_W2bb;
    const ushort_t* gW3ab = ws + O_W3ab;
    const ushort_t* gW3aT = ws + O_W3aT;
    const ushort_t* gW2bT = ws + O_W2bT;
    const ushort_t* gW2aT = ws + O_W2aT;

    f32x4 zk0, zk1, y3k0, y3k1;

    // ---- P1: stores/loads first (oldest), ring prologue last (newest);
    //      z = x@W1.T + b1 (y1 = z*z, z kept in regs); z2_3 = x@W3s.T + b3s.
    {
        float sc = scalar[0];
        int xr = tid >> 6, xc = tid & 63;
        float xd0 = xd[(R0 + xr) * 64 + xc];
        float xd1 = xd[(R0 + 16 + xr) * 64 + xc];
        out[YY_OFF + (R0 + xr) * 64 + xc] = sc;
        out[YY_OFF + (R0 + 16 + xr) * 64 + xc] = sc;
        const ushort_t* w1p = ws + O_W1b + (n0 + row16) * 64 + kq;
        const ushort_t* w3p = ws + O_W3sb + (n0 + row16) * 64 + kq;
        bf16x8 pb0 = *(const bf16x8*)(w1p);
        bf16x8 pb1 = *(const bf16x8*)(w1p + 32);
        bf16x8 pb2 = *(const bf16x8*)(w3p);
        bf16x8 pb3 = *(const bf16x8*)(w3p + 32);
        const float* xg0 = x + (R0 + row16) * 64;
        const float* xg1 = x + (R0 + 16 + row16) * 64;
        float4 xa0 = *(const float4*)(xg0 + kq);
        float4 xa1 = *(const float4*)(xg0 + kq + 4);
        float4 xa2 = *(const float4*)(xg0 + 32 + kq);
        float4 xa3 = *(const float4*)(xg0 + 32 + kq + 4);
        float4 xb0 = *(const float4*)(xg1 + kq);
        float4 xb1 = *(const float4*)(xg1 + kq + 4);
        float4 xb2 = *(const float4*)(xg1 + 32 + kq);
        float4 xb3 = *(const float4*)(xg1 + 32 + kq + 4);
        __builtin_amdgcn_sched_barrier(0);
        // ring prologue: units 0..3
        gload16(gW2ab + srcoff, rw);
        gload16(gW2bb + srcoff, rw + 512);
        gload16(gW2ab + srcoff + 32, rw + 1024);
        gload16(gW2bb + srcoff + 32, rw + 1536);
        __builtin_amdgcn_sched_barrier(0);
        sXd[tid] = xd0;
        sXd[tid + 1024] = xd1;
        if (tid < RPB) sNB[tid] = 0.f;
        union { ushort_t u[8]; bf16x8 v; } A0, A1, B0v, B1v;
#pragma unroll
        for (int j = 0; j < 4; j++) {
            A0.u[j]      = f2bf(((const float*)&xa0)[j]);
            A0.u[4 + j]  = f2bf(((const float*)&xa1)[j]);
            A1.u[j]      = f2bf(((const float*)&xa2)[j]);
            A1.u[4 + j]  = f2bf(((const float*)&xa3)[j]);
            B0v.u[j]     = f2bf(((const float*)&xb0)[j]);
            B0v.u[4 + j] = f2bf(((const float*)&xb1)[j]);
            B1v.u[j]     = f2bf(((const float*)&xb2)[j]);
            B1v.u[4 + j] = f2bf(((const float*)&xb3)[j]);
        }
        f32x4 z0 = {0.f,0.f,0.f,0.f}, z1 = {0.f,0.f,0.f,0.f};
        f32x4 q0 = {0.f,0.f,0.f,0.f}, q1 = {0.f,0.f,0.f,0.f};
        z0 = __builtin_amdgcn_mfma_f32_16x16x32_bf16(A0.v, pb0, z0, 0, 0, 0);
        z0 = __builtin_amdgcn_mfma_f32_16x16x32_bf16(A1.v, pb1, z0, 0, 0, 0);
        z1 = __builtin_amdgcn_mfma_f32_16x16x32_bf16(B0v.v, pb0, z1, 0, 0, 0);
        z1 = __builtin_amdgcn_mfma_f32_16x16x32_bf16(B1v.v, pb1, z1, 0, 0, 0);
        q0 = __builtin_amdgcn_mfma_f32_16x16x32_bf16(A0.v, pb2, q0, 0, 0, 0);
        q0 = __builtin_amdgcn_mfma_f32_16x16x32_bf16(A1.v, pb3, q0, 0, 0, 0);
        q1 = __builtin_amdgcn_mfma_f32_16x16x32_bf16(B0v.v, pb2, q1, 0, 0, 0);
        q1 = __builtin_amdgcn_mfma_f32_16x16x32_bf16(B1v.v, pb3, q1, 0, 0, 0);
        int c = n0 + row16;
        float bz = b1[c], bs = b3s[c];
#pragma unroll
        for (int i = 0; i < 4; i++) {
            int r = rq * 4 + i;
            int p0 = posw(r, c), p1 = posw(r + 16, c);
            float za = z0[i] + bz, zb = z1[i] + bz;
            zk0[i] = za; zk1[i] = zb;
            sY[p0] = f2bf(za * za);
            sY[p1] = f2bf(zb * zb);
            sZ23[p0] = f2bf(q0[i] + bs);
            sZ23[p1] = f2bf(q1[i] + bs);
        }
    }
    PHASE_BARRIER();

    // ---- P2 (ring 0..15): z1_2 = y1@W2a.T, z2_2 = y1@W2b.T; y2 -> sU
    {
        f32x4 a00 = {0.f,0.f,0.f,0.f}, a01 = {0.f,0.f,0.f,0.f};
        f32x4 a10 = {0.f,0.f,0.f,0.f}, a11 = {0.f,0.f,0.f,0.f};
        ring_phase<0, false>(gW2ab, gW2bb, gW3ab, gW3aT, sY, sY,
                             rw, srcoff, boff, kq, sw, a00, a01, a10, a11);
        int c = n0 + row16;
        float ba = b2a[c], bb = b2b[c];
#pragma unroll
        for (int i = 0; i < 4; i++) {
            int r = rq * 4 + i;
            int p0 = posw(r, c), p1 = posw(r + 16, c);
            float z12a = a00[i] + ba, z22a = a10[i] + bb;
            float z12b = a01[i] + ba, z22b = a11[i] + bb;
            sZ12[p0] = f2bf(z12a); sZ22[p0] = f2bf(z22a); sU[p0] = f2bf(z12a * z22a);
            sZ12[p1] = f2bf(z12b); sZ22[p1] = f2bf(z22b); sU[p1] = f2bf(z12b * z22b);
        }
    }
    PHASE_BARRIER();

    // ---- P4 (ring 16..31): z1_3 = y2@W3a.T + b3a; t = z2_3@(wout.w3a)T
    {
        f32x4 zz0 = {0.f,0.f,0.f,0.f}, zz1 = {0.f,0.f,0.f,0.f};
        f32x4 tt0 = {0.f,0.f,0.f,0.f}, tt1 = {0.f,0.f,0.f,0.f};
        ring_phase<1, false>(gW3ab, gW3aT, gW2bT, gW2aT, sU, sZ23,
                             rw, srcoff, boff, kq, sw, zz0, zz1, tt0, tt1);
        int c = n0 + row16;
        float ba = b3a[c], wo = wout[c];
#pragma unroll
        for (int i = 0; i < 4; i++) {
            int r = rq * 4 + i;
            int p0 = posw(r, c), p1 = posw(r + 16, c);
            float z13a = zz0[i] + ba, z23a = bf2f(sZ23[p0]);
            float z13b = zz1[i] + ba, z23b = bf2f(sZ23[p1]);
            float y3a = z13a * z23a, y3b = z13b * z23b;
            y3k0[i] = y3a; y3k1[i] = y3b;
            sY[p0] = f2bf(z13a);               // sY now holds z1_3
            sY[p1] = f2bf(z13b);
            sZ12[p0] = f2bf(tt0[i] * bf2f(sZ12[p0]));
            sZ22[p0] = f2bf(tt0[i] * bf2f(sZ22[p0]));
            sZ12[p1] = f2bf(tt1[i] * bf2f(sZ12[p1]));
            sZ22[p1] = f2bf(tt1[i] * bf2f(sZ22[p1]));
            float v0 = wo * y3a, v1 = wo * y3b;
            v0 += __shfl_xor(v0, 1); v0 += __shfl_xor(v0, 2);
            v0 += __shfl_xor(v0, 4); v0 += __shfl_xor(v0, 8);
            v1 += __shfl_xor(v1, 1); v1 += __shfl_xor(v1, 2);
            v1 += __shfl_xor(v1, 4); v1 += __shfl_xor(v1, 8);
            if (row16 == 0) { atomicAdd(&sNB[r], v0); atomicAdd(&sNB[r + 16], v1); }
        }
    }
    PHASE_BARRIER();

    // ---- P6 (ring 32..47): p = tz1@W2bT + tz2@W2aT ; c2 = 2*p*z -> sU
    {
        f32x4 pp0 = {0.f,0.f,0.f,0.f}, pp1 = {0.f,0.f,0.f,0.f};
        f32x4 d0 = {0.f,0.f,0.f,0.f}, d1 = {0.f,0.f,0.f,0.f};
        ring_phase<2, true>(gW2bT, gW2aT, gW2bT, gW2aT, sZ12, sZ22,
                            rw, srcoff, boff, kq, sw, pp0, pp1, d0, d1);
        int c = n0 + row16;
#pragma unroll
        for (int i = 0; i < 4; i++) {
            int r = rq * 4 + i;
            sU[posw(r, c)] = f2bf(2.f * pp0[i] * zk0[i]);
            sU[posw(r + 16, c)] = f2bf(2.f * pp1[i] * zk1[i]);
        }
    }
    PHASE_BARRIER();

    // ---- P7: y3 stores; fj1 = z1_3@(wout.w3s)T, fj2 = c2@W1T
    {
        int c = n0 + row16;
#pragma unroll
        for (int i = 0; i < 4; i++) {
            out[Y_OFF + (R0 + rq * 4 + i) * H + c] = y3k0[i];
            out[Y_OFF + (R0 + 16 + rq * 4 + i) * H + c] = y3k1[i];
        }
        int mat = wid >> 3, kh = (wid >> 2) & 1, nt = wid & 3;
        const ushort_t* Abase = mat ? sU : sY;
        const ushort_t* B = ws + (mat ? O_W1T : O_W3sT) + nt * 16 * H;
        float* dst = (float*)(mat ? sZ22 : sZ12) + kh * 2048;  // f32 [32][64] per kh
        int cc = nt * 16 + row16;
#pragma unroll
        for (int rg = 0; rg < 2; rg++) {
            f32x4 acc = {0.f,0.f,0.f,0.f};
            gemm_one<4, H, H>(Abase + rg * 16 * H, B, lane, kh * 128, acc);
#pragma unroll
            for (int i = 0; i < 4; i++)
                dst[(rg * 16 + rq * 4 + i) * 64 + cc] = acc[i];
        }
    }
    PHASE_BARRIER();

    // ---- P8: bdot + nb writes
    {
        float* F0 = (float*)sZ12;
        float* F1 = F0 + 2048;
        float* F2 = (float*)sZ22;
        float* F3 = F2 + 2048;
        int r = tid >> 5, j = tid & 31;
        int e = r * 64 + j, e2 = e + 32;
        float s = (F0[e] + F1[e] + F2[e] + F3[e]) * sXd[e] +
                  (F0[e2] + F1[e2] + F2[e2] + F3[e2]) * sXd[e2];
        s += __shfl_xor(s, 1);
        s += __shfl_xor(s, 2);
        s += __shfl_xor(s, 4);
        s += __shfl_xor(s, 8);
        s += __shfl_xor(s, 16);
        if (j == 0) out[BDOT_OFF + R0 + r] = s;
        if (tid < RPB) out[NB_OFF + R0 + tid] = sNB[tid];
    }
}

extern "C" void kernel_launch(void* const* d_in, const int* in_sizes, int n_in,
                              void* d_out, int out_size, void* d_ws, size_t ws_size,
                              hipStream_t stream) {
    (void)in_sizes; (void)n_in; (void)out_size; (void)ws_size;
    const float* x = (const float*)d_in[0];
    const float* xd = (const float*)d_in[1];
    const float* w1 = (const float*)d_in[2];
    const float* b1 = (const float*)d_in[3];
    const float* w2a = (const float*)d_in[4];
    const float* b2a = (const float*)d_in[5];
    const float* w2b = (const float*)d_in[6];
    const float* b2b = (const float*)d_in[7];
    const float* w3a = (const float*)d_in[8];
    const float* b3a = (const float*)d_in[9];
    const float* w3s = (const float*)d_in[10];
    const float* b3s = (const float*)d_in[11];
    const float* wout = (const float*)d_in[12];
    const float* scalar = (const float*)d_in[13];
    ushort_t* ws = (ushort_t*)d_ws;
    float* out = (float*)d_out;

    static bool attr_set = false;
    if (!attr_set) {
        hipFuncSetAttribute((const void*)net_main,
                            hipFuncAttributeMaxDynamicSharedMemorySize, SMEM_BYTES);
        attr_set = true;
    }

    prep_weights<<<112, 256, 0, stream>>>(w1, w2a, w2b, w3a, w3s, wout, ws);
    net_main<<<NBLK, 1024, SMEM_BYTES, stream>>>(x, xd, b1, b2a, b2b, b3a, b3s, wout, scalar, ws, out);
}